// Round 1
// baseline (131.063 us; speedup 1.0000x reference)
//
#include <hip/hip_runtime.h>

// Z: (2049, 8193) fp32, alpha: (1,) fp32.
// out = Z, except last row: out[2048, j] = Z[2048,j] + (alpha/N) * sum_{c<D} v[c]*(Z[c+D,j]-Z[c,j])
// where v[c] = sum_{j<N} Z[2048, j] * Z[c, j]   (j < N only: M kills column N)

#define D   1024
#define N   8192
#define DD  2049
#define N1  8193

#define NSPLIT  64     // c-splits for the correction partials
#define PSTRIDE 8196   // padded partial row stride in dwords (8193 -> x4 for 16B-aligned stores)

typedef float f32x4u __attribute__((ext_vector_type(4), aligned(4)));  // rows start at phase (r*8193)%4 dwords
typedef float f32x4a __attribute__((ext_vector_type(4), aligned(16)));

// ---------------- Kernel 1: row-parallel copy + fused dot ----------------
// grid = 2048 blocks (rows 0..2047; row 2048 is written by corr_finalize) x 512 threads.
// Each thread: 4 quads (16 floats). Rows r < 1024 also accumulate
// v[r] = dot(row, u) over j=0..8191 from the SAME registers.
__global__ void __launch_bounds__(512) copy_dot_rows(const float* __restrict__ Z,
                                                     float* __restrict__ out,
                                                     float* __restrict__ v) {
    const int r = blockIdx.x;
    const int t = threadIdx.x;
    const float* __restrict__ row  = Z   + (long)r * N1;
    float*       __restrict__ orow = out + (long)r * N1;
    const float* __restrict__ u    = Z   + (long)(DD - 1) * N1;   // 16B-aligned (2048*8193 % 4 == 0)

    if (r < D) {
        float acc = 0.f;
        #pragma unroll
        for (int it = 0; it < 4; ++it) {
            const int q = t + it * 512;          // quad 0..2047 -> j = 4q..4q+3 (j<8192)
            f32x4u a = *(const f32x4u*)(row + 4 * q);
            f32x4u b = *(const f32x4u*)(u   + 4 * q);
            __builtin_nontemporal_store(a, (f32x4u*)(orow + 4 * q));
            acc += a.x * b.x + a.y * b.y + a.z * b.z + a.w * b.w;
        }
        // reduce 512 threads: wave butterfly then 8-slot LDS
        #pragma unroll
        for (int off = 32; off > 0; off >>= 1)
            acc += __shfl_down(acc, off, 64);
        __shared__ float smem[8];
        if ((t & 63) == 0) smem[t >> 6] = acc;
        __syncthreads();
        if (t == 0) {
            float s = 0.f;
            #pragma unroll
            for (int w = 0; w < 8; ++w) s += smem[w];
            v[r] = s;
        }
    } else {
        #pragma unroll
        for (int it = 0; it < 4; ++it) {
            const int q = t + it * 512;
            f32x4u a = *(const f32x4u*)(row + 4 * q);
            __builtin_nontemporal_store(a, (f32x4u*)(orow + 4 * q));
        }
    }
    if (t == 511) orow[N] = row[N];              // tail element j = 8192 of each row
}

// ---------------- Kernel 2: correction partials (NO atomics) ----------------
// grid = (8, 64): x covers 2048 quads (j=0..8191), y = 64 splits of 16 c's.
// Each (j-range, c-split) block writes its private partial row: part[by][j].
// Z rows 0..2047 are L3-resident after kernel 1 (67 MB < 256 MB Infinity Cache).
__global__ void __launch_bounds__(256) corr_partial(const float* __restrict__ Z,
                                                    const float* __restrict__ v,
                                                    float* __restrict__ part) {
    const int q  = blockIdx.x * 256 + threadIdx.x;   // quad 0..2047
    const int j0 = q * 4;
    const int c0 = blockIdx.y * 16;
    float lx = 0.f, ly = 0.f, lz = 0.f, lw = 0.f;
    #pragma unroll
    for (int cc = 0; cc < 16; ++cc) {
        const int c = c0 + cc;
        const float vc = v[c];
        f32x4u zp = *(const f32x4u*)(Z + (long)(c + D) * N1 + j0);
        f32x4u zm = *(const f32x4u*)(Z + (long)c * N1 + j0);
        lx += vc * (zp.x - zm.x);
        ly += vc * (zp.y - zm.y);
        lz += vc * (zp.z - zm.z);
        lw += vc * (zp.w - zm.w);
    }
    f32x4a res = {lx, ly, lz, lw};
    __builtin_nontemporal_store(res, (f32x4a*)(part + (long)blockIdx.y * PSTRIDE + j0));
    // tail column j = 8192 (one thread per c-split)
    if (q == 0) {
        float lt = 0.f;
        #pragma unroll
        for (int cc = 0; cc < 16; ++cc) {
            const int c = c0 + cc;
            lt += v[c] * (Z[(long)(c + D) * N1 + N] - Z[(long)c * N1 + N]);
        }
        part[(long)blockIdx.y * PSTRIDE + N] = lt;
    }
}

// ---------------- Kernel 3: finalize last row ----------------
// out[2048, j] = Z[2048, j] + scale * sum_{s<64} part[s][j], for all j=0..8192.
// Reads 2 MB of partials (L2-resident) + 32 KB of Z's last row.
__global__ void __launch_bounds__(256) corr_finalize(const float* __restrict__ Z,
                                                     const float* __restrict__ part,
                                                     const float* __restrict__ alpha,
                                                     float* __restrict__ out) {
    const int tid = blockIdx.x * 256 + threadIdx.x;  // quad id 0..2048 (2048 = tail)
    if (tid > 2048) return;
    const float scale = alpha[0] / (float)N;
    const float* __restrict__ zl = Z   + (long)(DD - 1) * N1;    // 16B-aligned
    float*       __restrict__ o  = out + (long)(DD - 1) * N1;
    if (tid < 2048) {
        const int j0 = tid * 4;
        float sx = 0.f, sy = 0.f, sz = 0.f, sw = 0.f;
        #pragma unroll
        for (int s = 0; s < NSPLIT; ++s) {
            f32x4a p = *(const f32x4a*)(part + (long)s * PSTRIDE + j0);
            sx += p.x; sy += p.y; sz += p.z; sw += p.w;
        }
        f32x4a z = *(const f32x4a*)(zl + j0);
        f32x4a r = {z.x + scale * sx, z.y + scale * sy, z.z + scale * sz, z.w + scale * sw};
        *(f32x4a*)(o + j0) = r;
    } else {
        float s = 0.f;
        #pragma unroll
        for (int ss = 0; ss < NSPLIT; ++ss) s += part[(long)ss * PSTRIDE + N];
        o[N] = zl[N] + scale * s;
    }
}

extern "C" void kernel_launch(void* const* d_in, const int* in_sizes, int n_in,
                              void* d_out, int out_size, void* d_ws, size_t ws_size,
                              hipStream_t stream) {
    const float* Z     = (const float*)d_in[0];
    const float* alpha = (const float*)d_in[1];
    float* out  = (float*)d_out;
    float* v    = (float*)d_ws;                 // D floats = 4 KB scratch
    float* part = (float*)d_ws + 1024;          // 64 x 8196 floats = 2.1 MB, 16B-aligned

    copy_dot_rows<<<2048, 512, 0, stream>>>(Z, out, v);
    corr_partial<<<dim3(8, 64), 256, 0, stream>>>(Z, v, part);
    corr_finalize<<<9, 256, 0, stream>>>(Z, part, alpha, out);
}